// Round 2
// baseline (682.960 us; speedup 1.0000x reference)
//
#include <hip/hip_runtime.h>

typedef unsigned short u16;
typedef __attribute__((ext_vector_type(8))) short short8;
typedef __attribute__((ext_vector_type(4))) float f32x4;
typedef __attribute__((ext_vector_type(4))) unsigned short us4;

union S8U { short8 v; us4 h[2]; unsigned int u[4]; };

__device__ __forceinline__ u16 f2bf(float f){
  unsigned int u = __builtin_bit_cast(unsigned int, f);
  u += 0x7fffu + ((u >> 16) & 1u);
  return (u16)(u >> 16);
}
__device__ __forceinline__ float bf2f(u16 s){
  unsigned int u = ((unsigned int)s) << 16;
  return __builtin_bit_cast(float, u);
}
#define MFMA16(a,b,c) __builtin_amdgcn_mfma_f32_16x16x32_bf16((a),(b),(c),0,0,0)

// ---------------------------------------------------------------------------
// K0: prep — convert weights to bf16, build expanded rpe bias table, zero pooled
// ---------------------------------------------------------------------------
__global__ void k0_prep(const float* __restrict__ w_in, const float* __restrict__ w_out,
                        const float* __restrict__ rpe,
                        u16* __restrict__ wqkv_bf, u16* __restrict__ wout_bf,
                        u16* __restrict__ bias_bf, float* __restrict__ pooled){
  int gid = blockIdx.x * 256 + threadIdx.x;
  int stride = gridDim.x * 256;
  for (int idx = gid; idx < 83968; idx += stride) {
    if (idx < 49152) {
      wqkv_bf[idx] = f2bf(w_in[idx]);
    } else if (idx < 65536) {
      int i = idx - 49152; wout_bf[i] = f2bf(w_out[i]);
    } else if (idx < 81920) {
      int i = idx - 65536;
      int h = i >> 12, l = (i >> 6) & 63, m = i & 63;
      float v;
      if (m >= 49) v = -3.0e38f;       // mask pad key tokens
      else if (l >= 49) v = 0.0f;      // pad query rows: harmless
      else {
        int il = (l * 9363) >> 16, jl = l - il * 7;
        int im = (m * 9363) >> 16, jm = m - im * 7;
        int r = (il - im + 6) * 13 + (jl - jm + 6);
        v = rpe[r * 4 + h];
      }
      bias_bf[i] = f2bf(v);
    } else {
      pooled[idx - 81920] = 0.0f;
    }
  }
}

// ---------------------------------------------------------------------------
// K1: pooled sums per (b,c) via atomics.  grid 512 = 8 b x 64 slices, 256 thr
// ---------------------------------------------------------------------------
__global__ void k1_pool(const float* __restrict__ x, float* __restrict__ pooled){
  int b = blockIdx.x >> 6, s = blockIdx.x & 63;
  int t = threadIdx.x;
  int c4 = t & 31, r0 = t >> 5;
  const float4* xb = (const float4*)(x + ((size_t)b * 50176 + (size_t)s * 784) * 128);
  float4 acc = {0.f, 0.f, 0.f, 0.f};
  for (int i = 0; i < 98; ++i) {
    float4 v = xb[(size_t)(r0 + 8 * i) * 32 + c4];
    acc.x += v.x; acc.y += v.y; acc.z += v.z; acc.w += v.w;
  }
  float* p = pooled + b * 128 + c4 * 4;
  atomicAdd(p + 0, acc.x); atomicAdd(p + 1, acc.y);
  atomicAdd(p + 2, acc.z); atomicAdd(p + 3, acc.w);
}

// ---------------------------------------------------------------------------
// K2: tiny channel-attention MLP.  1 block x 128 threads
// ---------------------------------------------------------------------------
__global__ void k2_mlp(const float* __restrict__ pooled,
                       const float* __restrict__ w1, const float* __restrict__ b1,
                       const float* __restrict__ w2, const float* __restrict__ b2,
                       float* __restrict__ sca){
  __shared__ float hid[8][16];
  int t = threadIdx.x;
  int b = t >> 4, j = t & 15;
  float a = 0.f;
  for (int c = 0; c < 128; ++c) a += pooled[b * 128 + c] * w1[j * 128 + c];
  a = a * (1.0f / 50176.0f) + b1[j];
  hid[b][j] = fmaxf(a, 0.0f);
  __syncthreads();
  int c = t;
  for (int bb = 0; bb < 8; ++bb) {
    float v = b2[c];
    for (int jj = 0; jj < 16; ++jj) v += hid[bb][jj] * w2[c * 16 + jj];
    sca[bb * 128 + c] = 1.0f / (1.0f + __expf(-v));
  }
}

// ---------------------------------------------------------------------------
// K3: per-pixel mean/max over C of (x * s_ca).  8 lanes per pixel, coalesced.
// grid 8*1568, 256 thr (4 waves x 8 pixels)
// ---------------------------------------------------------------------------
__global__ void k3_stats(const float* __restrict__ x, const float* __restrict__ sca,
                         float* __restrict__ smean, float* __restrict__ smax){
  int b = blockIdx.x / 1568, chunk = blockIdx.x % 1568;
  int t = threadIdx.x, lane = t & 63, wv = t >> 6;
  int p = lane >> 3, c8 = lane & 7;
  const float4* sc = (const float4*)(sca + b * 128 + c8 * 16);
  float4 s0 = sc[0], s1 = sc[1], s2 = sc[2], s3 = sc[3];
  int pix = chunk * 32 + wv * 8 + p;
  const float4* row = (const float4*)(x + ((size_t)b * 50176 + pix) * 128 + c8 * 16);
  float4 v0 = row[0], v1 = row[1], v2 = row[2], v3 = row[3];
  float sum = 0.f, mx = -3.0e38f;
#define ACC4(V,S) { float a0=V.x*S.x, a1=V.y*S.y, a2=V.z*S.z, a3=V.w*S.w; \
                    sum += a0+a1+a2+a3; mx = fmaxf(mx, fmaxf(fmaxf(a0,a1), fmaxf(a2,a3))); }
  ACC4(v0,s0) ACC4(v1,s1) ACC4(v2,s2) ACC4(v3,s3)
#undef ACC4
  sum += __shfl_xor(sum, 1); sum += __shfl_xor(sum, 2); sum += __shfl_xor(sum, 4);
  mx = fmaxf(mx, __shfl_xor(mx, 1));
  mx = fmaxf(mx, __shfl_xor(mx, 2));
  mx = fmaxf(mx, __shfl_xor(mx, 4));
  if (c8 == 0) {
    smean[(size_t)b * 50176 + pix] = sum * (1.0f / 128.0f);
    smax [(size_t)b * 50176 + pix] = mx;
  }
}

// ---------------------------------------------------------------------------
// K4: 7x7 conv over {mean,max}, zero-padded, + sigmoid.  16x16 tiles.
// ---------------------------------------------------------------------------
__global__ void k4_conv(const float* __restrict__ smean, const float* __restrict__ smax,
                        const float* __restrict__ w, const float* __restrict__ sb,
                        float* __restrict__ ssa){
  __shared__ float tM[22 * 22], tX[22 * 22], wl[98];
  int b = blockIdx.x / 196, cell = blockIdx.x % 196;
  int y0 = (cell / 14) * 16, x0 = (cell % 14) * 16;
  int t = threadIdx.x;
  if (t < 98) wl[t] = w[t];
  for (int idx = t; idx < 484; idx += 256) {
    int yy = y0 - 3 + idx / 22, xx = x0 - 3 + idx % 22;
    bool ok = (yy >= 0 && yy < 224 && xx >= 0 && xx < 224);
    tM[idx] = ok ? smean[(size_t)b * 50176 + yy * 224 + xx] : 0.0f;
    tX[idx] = ok ? smax [(size_t)b * 50176 + yy * 224 + xx] : 0.0f;
  }
  __syncthreads();
  int ty = t >> 4, tx = t & 15;
  float acc = sb[0];
  for (int ky = 0; ky < 7; ++ky)
    for (int kx = 0; kx < 7; ++kx) {
      acc += wl[ky * 7 + kx]      * tM[(ty + ky) * 22 + tx + kx];
      acc += wl[49 + ky * 7 + kx] * tX[(ty + ky) * 22 + tx + kx];
    }
  ssa[(size_t)b * 50176 + (y0 + ty) * 224 + (x0 + tx)] = 1.0f / (1.0f + __expf(-acc));
}

// ---------------------------------------------------------------------------
// K5: fused window attention.  1 block = 1 window (49 tokens), 4 waves = 4 heads.
// LDS: qR [64][136] (xs staging -> q -> oo), kR [64][136], vR [128][68]. 51 KB.
// ---------------------------------------------------------------------------
__global__ __launch_bounds__(256) void k5_attn(
    const float* __restrict__ x, const float* __restrict__ sca, const float* __restrict__ ssa,
    const u16* __restrict__ wqkv, const u16* __restrict__ wout, const u16* __restrict__ biasb,
    const float* __restrict__ bin, const float* __restrict__ bout, float* __restrict__ out)
{
  __shared__ u16 lds[26112];
  u16* qR = lds;            // [64][136]
  u16* kR = lds + 8704;     // [64][136]
  u16* vR = lds + 17408;    // [128][68]

  int blk = blockIdx.x;
  int b = blk >> 10, ih = (blk >> 5) & 31, iw = blk & 31;
  int t = threadIdx.x, lane = t & 63, wv = t >> 6;
  int c15 = lane & 15, g4 = lane >> 4;

  // ---- stage xs = x * s_ca * s_sa  (bf16) into qR ----
  {
    int cq = t & 31, rr = t >> 5;
    const float* xb = x + (size_t)b * 50176 * 128;
    float4 s4 = *(const float4*)(sca + b * 128 + cq * 4);
    for (int p = 0; p < 7; ++p) {
      int r = p * 8 + rr;
      if (r < 49) {
        int i = (r * 9363) >> 16, j = r - i * 7;
        int hh = ih * 7 + i, ww = iw * 7 + j;
        float4 v = *(const float4*)(xb + ((size_t)(hh * 224 + ww)) * 128 + cq * 4);
        float ss = ssa[(size_t)b * 50176 + hh * 224 + ww];
        us4 o;
        o[0] = f2bf(v.x * s4.x * ss); o[1] = f2bf(v.y * s4.y * ss);
        o[2] = f2bf(v.z * s4.z * ss); o[3] = f2bf(v.w * s4.w * ss);
        *(us4*)(qR + r * 136 + cq * 4) = o;
      }
    }
    unsigned int* z = (unsigned int*)(qR + 49 * 136);
    for (int idx = t; idx < 1020; idx += 256) z[idx] = 0u;   // zero pad tokens
  }
  __syncthreads();

  // ---- load xs fragments (all of xs, per wave) ----
  short8 xsf[4][4];
#pragma unroll
  for (int nt = 0; nt < 4; ++nt)
#pragma unroll
    for (int ks = 0; ks < 4; ++ks)
      xsf[nt][ks] = *(const short8*)(qR + (16 * nt + c15) * 136 + 32 * ks + 8 * g4);
  __syncthreads();   // xs region now reusable

  // ---- qkv projection.  q,k transposed orientation (A=W,B=xs); v normal. ----
#pragma unroll
  for (int qi = 0; qi < 4; ++qi) {
    int mt = (qi < 2) ? (2 * wv + qi) : (8 + 2 * wv + qi - 2);
    short8 wf[4];
#pragma unroll
    for (int ks = 0; ks < 4; ++ks)
      wf[ks] = *(const short8*)(wqkv + (size_t)(16 * mt + c15) * 128 + 32 * ks + 8 * g4);
    float4 b4 = *(const float4*)(bin + 16 * mt + 4 * g4);
    bool isq = (qi < 2);
    float scl = isq ? 0.17677669529663689f : 1.0f;
    u16* dst = isq ? qR : kR;
    int dcol = isq ? (16 * mt) : (16 * (mt - 8));
#pragma unroll
    for (int nt = 0; nt < 4; ++nt) {
      f32x4 acc = {0.f, 0.f, 0.f, 0.f};
#pragma unroll
      for (int ks = 0; ks < 4; ++ks) acc = MFMA16(wf[ks], xsf[nt][ks], acc);
      us4 o;
      o[0] = f2bf((acc[0] + b4.x) * scl); o[1] = f2bf((acc[1] + b4.y) * scl);
      o[2] = f2bf((acc[2] + b4.z) * scl); o[3] = f2bf((acc[3] + b4.w) * scl);
      *(us4*)(dst + (16 * nt + c15) * 136 + dcol + 4 * g4) = o;
    }
  }
#pragma unroll
  for (int vi = 0; vi < 2; ++vi) {
    int ntv = 2 * wv + vi;
    short8 wf[4];
#pragma unroll
    for (int ks = 0; ks < 4; ++ks)
      wf[ks] = *(const short8*)(wqkv + (size_t)(256 + 16 * ntv + c15) * 128 + 32 * ks + 8 * g4);
    float bv = bin[256 + 16 * ntv + c15];
#pragma unroll
    for (int mt = 0; mt < 4; ++mt) {
      f32x4 acc = {0.f, 0.f, 0.f, 0.f};
#pragma unroll
      for (int ks = 0; ks < 4; ++ks) acc = MFMA16(xsf[mt][ks], wf[ks], acc);
      us4 o;
      o[0] = f2bf(acc[0] + bv); o[1] = f2bf(acc[1] + bv);
      o[2] = f2bf(acc[2] + bv); o[3] = f2bf(acc[3] + bv);
      *(us4*)(vR + (16 * ntv + c15) * 68 + 16 * mt + 4 * g4) = o;
    }
  }
  // no barrier: q/k/v slices consumed below are wave-local (wave wv wrote cols [32wv,32wv+32))

  // ---- scores_t[m][l] = k . q  for head wv; +bias; softmax over m ----
  short8 kf[4], qf[4];
#pragma unroll
  for (int mt = 0; mt < 4; ++mt)
    kf[mt] = *(const short8*)(kR + (16 * mt + c15) * 136 + 32 * wv + 8 * g4);
#pragma unroll
  for (int nt = 0; nt < 4; ++nt)
    qf[nt] = *(const short8*)(qR + (16 * nt + c15) * 136 + 32 * wv + 8 * g4);
  f32x4 sc[4][4];
#pragma unroll
  for (int mt = 0; mt < 4; ++mt)
#pragma unroll
    for (int nt = 0; nt < 4; ++nt) {
      f32x4 zz = {0.f, 0.f, 0.f, 0.f};
      sc[mt][nt] = MFMA16(kf[mt], qf[nt], zz);
    }
#pragma unroll
  for (int mt = 0; mt < 4; ++mt)
#pragma unroll
    for (int nt = 0; nt < 4; ++nt) {
      us4 bb = *(const us4*)(biasb + (size_t)((wv * 64 + 16 * nt + c15) * 64 + 16 * mt + 4 * g4));
      sc[mt][nt][0] += bf2f(bb[0]); sc[mt][nt][1] += bf2f(bb[1]);
      sc[mt][nt][2] += bf2f(bb[2]); sc[mt][nt][3] += bf2f(bb[3]);
    }
  unsigned int pk[4][4][2];
#pragma unroll
  for (int nt = 0; nt < 4; ++nt) {
    float m = -3.0e38f;
#pragma unroll
    for (int mt = 0; mt < 4; ++mt)
      m = fmaxf(m, fmaxf(fmaxf(sc[mt][nt][0], sc[mt][nt][1]),
                         fmaxf(sc[mt][nt][2], sc[mt][nt][3])));
    m = fmaxf(m, __shfl_xor(m, 16));
    m = fmaxf(m, __shfl_xor(m, 32));
    float s = 0.f;
#pragma unroll
    for (int mt = 0; mt < 4; ++mt)
#pragma unroll
      for (int r = 0; r < 4; ++r) {
        float e = __expf(sc[mt][nt][r] - m);
        sc[mt][nt][r] = e; s += e;
      }
    s += __shfl_xor(s, 16);
    s += __shfl_xor(s, 32);
    float rs = 1.0f / s;
#pragma unroll
    for (int mt = 0; mt < 4; ++mt) {
      pk[mt][nt][0] = (unsigned)f2bf(sc[mt][nt][0] * rs) | ((unsigned)f2bf(sc[mt][nt][1] * rs) << 16);
      pk[mt][nt][1] = (unsigned)f2bf(sc[mt][nt][2] * rs) | ((unsigned)f2bf(sc[mt][nt][3] * rs) << 16);
    }
  }

  // ---- PV: out_t[d][l] = v_t . attn   (B-fragment assembled in-register) ----
  f32x4 oacc[2][4];
  const f32x4 zero4 = {0.f, 0.f, 0.f, 0.f};
#pragma unroll
  for (int dt = 0; dt < 2; ++dt)
#pragma unroll
    for (int nt = 0; nt < 4; ++nt) oacc[dt][nt] = zero4;
#pragma unroll
  for (int ks = 0; ks < 2; ++ks) {
    short8 va[2];
#pragma unroll
    for (int dt = 0; dt < 2; ++dt) {
      S8U u;
      u.h[0] = *(const us4*)(vR + (32 * wv + 16 * dt + c15) * 68 + 32 * ks + 4 * g4);
      u.h[1] = *(const us4*)(vR + (32 * wv + 16 * dt + c15) * 68 + 32 * ks + 16 + 4 * g4);
      va[dt] = u.v;
    }
#pragma unroll
    for (int nt = 0; nt < 4; ++nt) {
      S8U pb;
      pb.u[0] = pk[2 * ks][nt][0];     pb.u[1] = pk[2 * ks][nt][1];
      pb.u[2] = pk[2 * ks + 1][nt][0]; pb.u[3] = pk[2 * ks + 1][nt][1];
#pragma unroll
      for (int dt = 0; dt < 2; ++dt)
        oacc[dt][nt] = MFMA16(va[dt], pb.v, oacc[dt][nt]);
    }
  }
  // write oo (attention output, [l][d]) into qR region (own column slice)
#pragma unroll
  for (int dt = 0; dt < 2; ++dt)
#pragma unroll
    for (int nt = 0; nt < 4; ++nt) {
      us4 o;
      o[0] = f2bf(oacc[dt][nt][0]); o[1] = f2bf(oacc[dt][nt][1]);
      o[2] = f2bf(oacc[dt][nt][2]); o[3] = f2bf(oacc[dt][nt][3]);
      *(us4*)(qR + (16 * nt + c15) * 136 + 32 * wv + 16 * dt + 4 * g4) = o;
    }
  __syncthreads();   // all heads' oo written

  // ---- out projection + store ----
  short8 oof[4][4];
#pragma unroll
  for (int mt = 0; mt < 4; ++mt)
#pragma unroll
    for (int ks = 0; ks < 4; ++ks)
      oof[mt][ks] = *(const short8*)(qR + (16 * mt + c15) * 136 + 32 * ks + 8 * g4);
  float* ob = out + (size_t)b * 50176 * 128;
#pragma unroll
  for (int oi = 0; oi < 2; ++oi) {
    int nto = 2 * wv + oi;
    short8 wf[4];
#pragma unroll
    for (int ks = 0; ks < 4; ++ks)
      wf[ks] = *(const short8*)(wout + (size_t)(16 * nto + c15) * 128 + 32 * ks + 8 * g4);
    float bo = bout[16 * nto + c15];
#pragma unroll
    for (int mt = 0; mt < 4; ++mt) {
      f32x4 acc = {0.f, 0.f, 0.f, 0.f};
#pragma unroll
      for (int ks = 0; ks < 4; ++ks) acc = MFMA16(oof[mt][ks], wf[ks], acc);
#pragma unroll
      for (int r = 0; r < 4; ++r) {
        int tok = 16 * mt + 4 * g4 + r;
        if (tok < 49) {
          int i = (tok * 9363) >> 16, j = tok - i * 7;
          int hh = ih * 7 + i, ww = iw * 7 + j;
          ob[((size_t)(hh * 224 + ww)) * 128 + 16 * nto + c15] = acc[r] + bo;
        }
      }
    }
  }
}

// ---------------------------------------------------------------------------
extern "C" void kernel_launch(void* const* d_in, const int* in_sizes, int n_in,
                              void* d_out, int out_size, void* d_ws, size_t ws_size,
                              hipStream_t stream) {
  const float* x     = (const float*)d_in[0];
  const float* ca_w1 = (const float*)d_in[3];
  const float* ca_b1 = (const float*)d_in[4];
  const float* ca_w2 = (const float*)d_in[5];
  const float* ca_b2 = (const float*)d_in[6];
  const float* sa_w  = (const float*)d_in[7];
  const float* sa_b  = (const float*)d_in[8];
  const float* w_in  = (const float*)d_in[9];
  const float* b_in  = (const float*)d_in[10];
  const float* w_out = (const float*)d_in[11];
  const float* b_out = (const float*)d_in[12];
  const float* rpe   = (const float*)d_in[13];
  float* out = (float*)d_out;

  char* ws = (char*)d_ws;
  float* pooled = (float*)(ws + 0);                       // 1024 f32
  float* sca    = (float*)(ws + 4096);                    // 1024 f32
  float* smean  = (float*)(ws + 8192);                    // 401408 f32
  float* smax   = (float*)(ws + 8192 + 1605632);          // 401408 f32
  float* ssa    = (float*)(ws + 8192 + 2 * 1605632);      // 401408 f32
  u16* wqkv_bf  = (u16*)(ws + 8192 + 3 * 1605632);                 // 49152 u16
  u16* wout_bf  = (u16*)(ws + 8192 + 3 * 1605632 + 98304);         // 16384 u16
  u16* bias_bf  = (u16*)(ws + 8192 + 3 * 1605632 + 98304 + 32768); // 16384 u16

  k0_prep<<<328, 256, 0, stream>>>(w_in, w_out, rpe, wqkv_bf, wout_bf, bias_bf, pooled);
  k1_pool<<<512, 256, 0, stream>>>(x, pooled);
  k2_mlp <<<1, 128, 0, stream>>>(pooled, ca_w1, ca_b1, ca_w2, ca_b2, sca);
  k3_stats<<<12544, 256, 0, stream>>>(x, sca, smean, smax);
  k4_conv<<<1568, 256, 0, stream>>>(smean, smax, sa_w, sa_b, ssa);
  k5_attn<<<8192, 256, 0, stream>>>(x, sca, ssa, wqkv_bf, wout_bf, bias_bf, b_in, b_out, out);
}

// Round 5
// 659.686 us; speedup vs baseline: 1.0353x; 1.0353x over previous
//
#include <hip/hip_runtime.h>

typedef unsigned short u16;
typedef __attribute__((ext_vector_type(8))) short short8;
typedef __attribute__((ext_vector_type(4))) float f32x4;
typedef __attribute__((ext_vector_type(4))) unsigned short us4;
typedef __attribute__((ext_vector_type(2))) unsigned int u32x2;

union S8U { short8 v; us4 h[2]; unsigned int u[4]; };

__device__ __forceinline__ u16 f2bf(float f){
  unsigned int u = __builtin_bit_cast(unsigned int, f);
  u += 0x7fffu + ((u >> 16) & 1u);
  return (u16)(u >> 16);
}
__device__ __forceinline__ float bf2f(u16 s){
  unsigned int u = ((unsigned int)s) << 16;
  return __builtin_bit_cast(float, u);
}
// HW packed f32->bf16 (RNE), 1 VALU op per 2 values
__device__ __forceinline__ unsigned int cvt2(float a, float b){
  unsigned int r;
  asm("v_cvt_pk_bf16_f32 %0, %1, %2" : "=v"(r) : "v"(a), "v"(b));
  return r;
}
#define MFMA16(a,b,c) __builtin_amdgcn_mfma_f32_16x16x32_bf16((a),(b),(c),0,0,0)

// ---------------------------------------------------------------------------
// K0: prep — convert weights to bf16, build expanded rpe bias table, zero pooled
// ---------------------------------------------------------------------------
__global__ void k0_prep(const float* __restrict__ w_in, const float* __restrict__ w_out,
                        const float* __restrict__ rpe,
                        u16* __restrict__ wqkv_bf, u16* __restrict__ wout_bf,
                        u16* __restrict__ bias_bf, float* __restrict__ pooled){
  int gid = blockIdx.x * 256 + threadIdx.x;
  int stride = gridDim.x * 256;
  for (int idx = gid; idx < 83968; idx += stride) {
    if (idx < 49152) {
      wqkv_bf[idx] = f2bf(w_in[idx]);
    } else if (idx < 65536) {
      int i = idx - 49152; wout_bf[i] = f2bf(w_out[i]);
    } else if (idx < 81920) {
      int i = idx - 65536;
      int h = i >> 12, l = (i >> 6) & 63, m = i & 63;
      float v;
      if (m >= 49) v = -3.0e38f;       // mask pad key tokens
      else if (l >= 49) v = 0.0f;      // pad query rows: harmless
      else {
        int il = (l * 9363) >> 16, jl = l - il * 7;
        int im = (m * 9363) >> 16, jm = m - im * 7;
        int r = (il - im + 6) * 13 + (jl - jm + 6);
        v = rpe[r * 4 + h];
      }
      bias_bf[i] = f2bf(v);
    } else {
      pooled[idx - 81920] = 0.0f;
    }
  }
}

// ---------------------------------------------------------------------------
// K1: pooled sums per (b,c).  3136 blocks (12/CU), 128 pixels/block,
// intra-block reduce (shfl + LDS), 128 atomics/block.
// ---------------------------------------------------------------------------
__global__ void k1_pool(const float* __restrict__ x, float* __restrict__ pooled){
  __shared__ float4 red[4][32];
  int b = blockIdx.x / 392, s = blockIdx.x % 392;
  int t = threadIdx.x;
  int c4 = t & 31, r0 = t >> 5;
  const float4* xb = (const float4*)x + ((size_t)b * 50176 + (size_t)s * 128) * 32;
  float4 acc = {0.f, 0.f, 0.f, 0.f};
#pragma unroll
  for (int i = 0; i < 16; ++i) {
    float4 v = xb[(size_t)(r0 + 8 * i) * 32 + c4];
    acc.x += v.x; acc.y += v.y; acc.z += v.z; acc.w += v.w;
  }
  acc.x += __shfl_xor(acc.x, 32); acc.y += __shfl_xor(acc.y, 32);
  acc.z += __shfl_xor(acc.z, 32); acc.w += __shfl_xor(acc.w, 32);
  if ((t & 63) < 32) red[t >> 6][c4] = acc;
  __syncthreads();
  if (t < 32) {
    float4 a0 = red[0][t], a1 = red[1][t], a2 = red[2][t], a3 = red[3][t];
    float sx = a0.x + a1.x + a2.x + a3.x;
    float sy = a0.y + a1.y + a2.y + a3.y;
    float sz = a0.z + a1.z + a2.z + a3.z;
    float sw = a0.w + a1.w + a2.w + a3.w;
    float* p = pooled + b * 128 + t * 4;
    atomicAdd(p + 0, sx); atomicAdd(p + 1, sy);
    atomicAdd(p + 2, sz); atomicAdd(p + 3, sw);
  }
}

// ---------------------------------------------------------------------------
// K2: tiny channel-attention MLP.  1 block x 128 threads
// ---------------------------------------------------------------------------
__global__ void k2_mlp(const float* __restrict__ pooled,
                       const float* __restrict__ w1, const float* __restrict__ b1,
                       const float* __restrict__ w2, const float* __restrict__ b2,
                       float* __restrict__ sca){
  __shared__ float hid[8][16];
  int t = threadIdx.x;
  int b = t >> 4, j = t & 15;
  float a = 0.f;
  for (int c = 0; c < 128; ++c) a += pooled[b * 128 + c] * w1[j * 128 + c];
  a = a * (1.0f / 50176.0f) + b1[j];
  hid[b][j] = fmaxf(a, 0.0f);
  __syncthreads();
  int c = t;
  for (int bb = 0; bb < 8; ++bb) {
    float v = b2[c];
    for (int jj = 0; jj < 16; ++jj) v += hid[bb][jj] * w2[c * 16 + jj];
    sca[bb * 128 + c] = 1.0f / (1.0f + __expf(-v));
  }
}

// ---------------------------------------------------------------------------
// K3: per-pixel mean/max over C of (x * s_ca).  8 lanes per pixel, coalesced.
// grid 8*1568, 256 thr (4 waves x 8 pixels)
// ---------------------------------------------------------------------------
__global__ void k3_stats(const float* __restrict__ x, const float* __restrict__ sca,
                         float* __restrict__ smean, float* __restrict__ smax){
  int b = blockIdx.x / 1568, chunk = blockIdx.x % 1568;
  int t = threadIdx.x, lane = t & 63, wv = t >> 6;
  int p = lane >> 3, c8 = lane & 7;
  const float4* sc = (const float4*)(sca + b * 128 + c8 * 16);
  float4 s0 = sc[0], s1 = sc[1], s2 = sc[2], s3 = sc[3];
  int pix = chunk * 32 + wv * 8 + p;
  const float4* row = (const float4*)(x + ((size_t)b * 50176 + pix) * 128 + c8 * 16);
  float4 v0 = row[0], v1 = row[1], v2 = row[2], v3 = row[3];
  float sum = 0.f, mx = -3.0e38f;
#define ACC4(V,S) { float a0=V.x*S.x, a1=V.y*S.y, a2=V.z*S.z, a3=V.w*S.w; \
                    sum += a0+a1+a2+a3; mx = fmaxf(mx, fmaxf(fmaxf(a0,a1), fmaxf(a2,a3))); }
  ACC4(v0,s0) ACC4(v1,s1) ACC4(v2,s2) ACC4(v3,s3)
#undef ACC4
  sum += __shfl_xor(sum, 1); sum += __shfl_xor(sum, 2); sum += __shfl_xor(sum, 4);
  mx = fmaxf(mx, __shfl_xor(mx, 1));
  mx = fmaxf(mx, __shfl_xor(mx, 2));
  mx = fmaxf(mx, __shfl_xor(mx, 4));
  if (c8 == 0) {
    smean[(size_t)b * 50176 + pix] = sum * (1.0f / 128.0f);
    smax [(size_t)b * 50176 + pix] = mx;
  }
}

// ---------------------------------------------------------------------------
// K4: 7x7 conv over {mean,max}, zero-padded, + sigmoid.  16x16 tiles.
// ---------------------------------------------------------------------------
__global__ void k4_conv(const float* __restrict__ smean, const float* __restrict__ smax,
                        const float* __restrict__ w, const float* __restrict__ sb,
                        float* __restrict__ ssa){
  __shared__ float tM[22 * 22], tX[22 * 22], wl[98];
  int b = blockIdx.x / 196, cell = blockIdx.x % 196;
  int y0 = (cell / 14) * 16, x0 = (cell % 14) * 16;
  int t = threadIdx.x;
  if (t < 98) wl[t] = w[t];
  for (int idx = t; idx < 484; idx += 256) {
    int yy = y0 - 3 + idx / 22, xx = x0 - 3 + idx % 22;
    bool ok = (yy >= 0 && yy < 224 && xx >= 0 && xx < 224);
    tM[idx] = ok ? smean[(size_t)b * 50176 + yy * 224 + xx] : 0.0f;
    tX[idx] = ok ? smax [(size_t)b * 50176 + yy * 224 + xx] : 0.0f;
  }
  __syncthreads();
  int ty = t >> 4, tx = t & 15;
  float acc = sb[0];
  for (int ky = 0; ky < 7; ++ky)
    for (int kx = 0; kx < 7; ++kx) {
      acc += wl[ky * 7 + kx]      * tM[(ty + ky) * 22 + tx + kx];
      acc += wl[49 + ky * 7 + kx] * tX[(ty + ky) * 22 + tx + kx];
    }
  ssa[(size_t)b * 50176 + (y0 + ty) * 224 + (x0 + tx)] = 1.0f / (1.0f + __expf(-acc));
}

// ---------------------------------------------------------------------------
// K5: fused window attention.  1 block = 1 window (49 tokens), 4 waves = 4 heads.
// LDS: qR [64][136] (xs staging -> q -> oo), kR [64][136], vR [128][68]. 51 KB.
// Output restaged as f32 in kR/vR region -> coalesced float4 stores.
// ---------------------------------------------------------------------------
__global__ __launch_bounds__(256) void k5_attn(
    const float* __restrict__ x, const float* __restrict__ sca, const float* __restrict__ ssa,
    const u16* __restrict__ wqkv, const u16* __restrict__ wout, const u16* __restrict__ biasb,
    const float* __restrict__ bin, const float* __restrict__ bout, float* __restrict__ out)
{
  __shared__ u16 lds[26112];
  u16* qR = lds;            // [64][136]
  u16* kR = lds + 8704;     // [64][136]
  u16* vR = lds + 17408;    // [128][68]
  float* fbuf = (float*)(lds + 8704);  // f32 [64][132] overlay on kR+vR (out restage)

  int blk = blockIdx.x;
  int b = blk >> 10, ih = (blk >> 5) & 31, iw = blk & 31;
  int t = threadIdx.x, lane = t & 63, wv = t >> 6;
  int c15 = lane & 15, g4 = lane >> 4;

  // ---- stage xs = x * s_ca * s_sa  (bf16) into qR ----
  {
    int cq = t & 31, rr = t >> 5;
    const float* xb = x + (size_t)b * 50176 * 128;
    float4 s4 = *(const float4*)(sca + b * 128 + cq * 4);
    for (int p = 0; p < 7; ++p) {
      int r = p * 8 + rr;
      if (r < 49) {
        int i = (r * 9363) >> 16, j = r - i * 7;
        int hh = ih * 7 + i, ww = iw * 7 + j;
        float4 v = *(const float4*)(xb + ((size_t)(hh * 224 + ww)) * 128 + cq * 4);
        float ss = ssa[(size_t)b * 50176 + hh * 224 + ww];
        u32x2 o;
        o[0] = cvt2(v.x * s4.x * ss, v.y * s4.y * ss);
        o[1] = cvt2(v.z * s4.z * ss, v.w * s4.w * ss);
        *(u32x2*)(qR + r * 136 + cq * 4) = o;
      }
    }
    unsigned int* z = (unsigned int*)(qR + 49 * 136);
    for (int idx = t; idx < 1020; idx += 256) z[idx] = 0u;   // zero pad tokens
  }
  __syncthreads();

  // ---- load xs fragments (all of xs, per wave) ----
  short8 xsf[4][4];
#pragma unroll
  for (int nt = 0; nt < 4; ++nt)
#pragma unroll
    for (int ks = 0; ks < 4; ++ks)
      xsf[nt][ks] = *(const short8*)(qR + (16 * nt + c15) * 136 + 32 * ks + 8 * g4);
  __syncthreads();   // xs region now reusable

  // ---- qkv projection.  q,k transposed orientation (A=W,B=xs); v normal. ----
#pragma unroll
  for (int qi = 0; qi < 4; ++qi) {
    int mt = (qi < 2) ? (2 * wv + qi) : (8 + 2 * wv + qi - 2);
    short8 wf[4];
#pragma unroll
    for (int ks = 0; ks < 4; ++ks)
      wf[ks] = *(const short8*)(wqkv + (size_t)(16 * mt + c15) * 128 + 32 * ks + 8 * g4);
    float4 b4 = *(const float4*)(bin + 16 * mt + 4 * g4);
    bool isq = (qi < 2);
    float scl = isq ? 0.17677669529663689f : 1.0f;
    u16* dst = isq ? qR : kR;
    int dcol = isq ? (16 * mt) : (16 * (mt - 8));
#pragma unroll
    for (int nt = 0; nt < 4; ++nt) {
      f32x4 acc = {0.f, 0.f, 0.f, 0.f};
#pragma unroll
      for (int ks = 0; ks < 4; ++ks) acc = MFMA16(wf[ks], xsf[nt][ks], acc);
      u32x2 o;
      o[0] = cvt2((acc[0] + b4.x) * scl, (acc[1] + b4.y) * scl);
      o[1] = cvt2((acc[2] + b4.z) * scl, (acc[3] + b4.w) * scl);
      *(u32x2*)(dst + (16 * nt + c15) * 136 + dcol + 4 * g4) = o;
    }
  }
#pragma unroll
  for (int vi = 0; vi < 2; ++vi) {
    int ntv = 2 * wv + vi;
    short8 wf[4];
#pragma unroll
    for (int ks = 0; ks < 4; ++ks)
      wf[ks] = *(const short8*)(wqkv + (size_t)(256 + 16 * ntv + c15) * 128 + 32 * ks + 8 * g4);
    float bv = bin[256 + 16 * ntv + c15];
#pragma unroll
    for (int mt = 0; mt < 4; ++mt) {
      f32x4 acc = {0.f, 0.f, 0.f, 0.f};
#pragma unroll
      for (int ks = 0; ks < 4; ++ks) acc = MFMA16(xsf[mt][ks], wf[ks], acc);
      u32x2 o;
      o[0] = cvt2(acc[0] + bv, acc[1] + bv);
      o[1] = cvt2(acc[2] + bv, acc[3] + bv);
      *(u32x2*)(vR + (16 * ntv + c15) * 68 + 16 * mt + 4 * g4) = o;
    }
  }
  // no barrier: q/k/v slices consumed below are wave-local (wave wv wrote cols [32wv,32wv+32))

  // ---- scores_t[m][l] = k . q  for head wv; +bias; softmax over m ----
  short8 kf[4], qf[4];
#pragma unroll
  for (int mt = 0; mt < 4; ++mt)
    kf[mt] = *(const short8*)(kR + (16 * mt + c15) * 136 + 32 * wv + 8 * g4);
#pragma unroll
  for (int nt = 0; nt < 4; ++nt)
    qf[nt] = *(const short8*)(qR + (16 * nt + c15) * 136 + 32 * wv + 8 * g4);
  f32x4 sc[4][4];
#pragma unroll
  for (int mt = 0; mt < 4; ++mt)
#pragma unroll
    for (int nt = 0; nt < 4; ++nt) {
      f32x4 zz = {0.f, 0.f, 0.f, 0.f};
      sc[mt][nt] = MFMA16(kf[mt], qf[nt], zz);
    }
#pragma unroll
  for (int mt = 0; mt < 4; ++mt)
#pragma unroll
    for (int nt = 0; nt < 4; ++nt) {
      us4 bb = *(const us4*)(biasb + (size_t)((wv * 64 + 16 * nt + c15) * 64 + 16 * mt + 4 * g4));
      sc[mt][nt][0] += bf2f(bb[0]); sc[mt][nt][1] += bf2f(bb[1]);
      sc[mt][nt][2] += bf2f(bb[2]); sc[mt][nt][3] += bf2f(bb[3]);
    }
  unsigned int pk[4][4][2];
#pragma unroll
  for (int nt = 0; nt < 4; ++nt) {
    float m = -3.0e38f;
#pragma unroll
    for (int mt = 0; mt < 4; ++mt)
      m = fmaxf(m, fmaxf(fmaxf(sc[mt][nt][0], sc[mt][nt][1]),
                         fmaxf(sc[mt][nt][2], sc[mt][nt][3])));
    m = fmaxf(m, __shfl_xor(m, 16));
    m = fmaxf(m, __shfl_xor(m, 32));
    float s = 0.f;
#pragma unroll
    for (int mt = 0; mt < 4; ++mt)
#pragma unroll
      for (int r = 0; r < 4; ++r) {
        float e = __expf(sc[mt][nt][r] - m);
        sc[mt][nt][r] = e; s += e;
      }
    s += __shfl_xor(s, 16);
    s += __shfl_xor(s, 32);
    float rs = 1.0f / s;
#pragma unroll
    for (int mt = 0; mt < 4; ++mt) {
      pk[mt][nt][0] = cvt2(sc[mt][nt][0] * rs, sc[mt][nt][1] * rs);
      pk[mt][nt][1] = cvt2(sc[mt][nt][2] * rs, sc[mt][nt][3] * rs);
    }
  }

  // ---- PV: out_t[d][l] = v_t . attn   (B-fragment assembled in-register) ----
  f32x4 oacc[2][4];
  const f32x4 zero4 = {0.f, 0.f, 0.f, 0.f};
#pragma unroll
  for (int dt = 0; dt < 2; ++dt)
#pragma unroll
    for (int nt = 0; nt < 4; ++nt) oacc[dt][nt] = zero4;
#pragma unroll
  for (int ks = 0; ks < 2; ++ks) {
    short8 va[2];
#pragma unroll
    for (int dt = 0; dt < 2; ++dt) {
      S8U u;
      u.h[0] = *(const us4*)(vR + (32 * wv + 16 * dt + c15) * 68 + 32 * ks + 4 * g4);
      u.h[1] = *(const us4*)(vR + (32 * wv + 16 * dt + c15) * 68 + 32 * ks + 16 + 4 * g4);
      va[dt] = u.v;
    }
#pragma unroll
    for (int nt = 0; nt < 4; ++nt) {
      S8U pb;
      pb.u[0] = pk[2 * ks][nt][0];     pb.u[1] = pk[2 * ks][nt][1];
      pb.u[2] = pk[2 * ks + 1][nt][0]; pb.u[3] = pk[2 * ks + 1][nt][1];
#pragma unroll
      for (int dt = 0; dt < 2; ++dt)
        oacc[dt][nt] = MFMA16(va[dt], pb.v, oacc[dt][nt]);
    }
  }
  // write oo (attention output, [l][d]) into qR region (own column slice)
#pragma unroll
  for (int dt = 0; dt < 2; ++dt)
#pragma unroll
    for (int nt = 0; nt < 4; ++nt) {
      u32x2 o;
      o[0] = cvt2(oacc[dt][nt][0], oacc[dt][nt][1]);
      o[1] = cvt2(oacc[dt][nt][2], oacc[dt][nt][3]);
      *(u32x2*)(qR + (16 * nt + c15) * 136 + 32 * wv + 16 * dt + 4 * g4) = o;
    }
  __syncthreads();   // all heads' oo written

  // ---- out projection -> f32 restage in fbuf (kR/vR region, now dead) ----
  short8 oof[4][4];
#pragma unroll
  for (int mt = 0; mt < 4; ++mt)
#pragma unroll
    for (int ks = 0; ks < 4; ++ks)
      oof[mt][ks] = *(const short8*)(qR + (16 * mt + c15) * 136 + 32 * ks + 8 * g4);
#pragma unroll
  for (int oi = 0; oi < 2; ++oi) {
    int nto = 2 * wv + oi;
    short8 wf[4];
#pragma unroll
    for (int ks = 0; ks < 4; ++ks)
      wf[ks] = *(const short8*)(wout + (size_t)(16 * nto + c15) * 128 + 32 * ks + 8 * g4);
    float bo = bout[16 * nto + c15];
#pragma unroll
    for (int mt = 0; mt < 4; ++mt) {
      f32x4 acc = {0.f, 0.f, 0.f, 0.f};
#pragma unroll
      for (int ks = 0; ks < 4; ++ks) acc = MFMA16(oof[mt][ks], wf[ks], acc);
#pragma unroll
      for (int r = 0; r < 4; ++r)
        fbuf[(16 * mt + 4 * g4 + r) * 132 + 16 * nto + c15] = acc[r] + bo;
    }
  }
  __syncthreads();   // fbuf complete

  // ---- coalesced float4 store of 49 tokens x 128 ch ----
  {
    float* ob = out + (size_t)b * 50176 * 128;
    int rr = t >> 5, c = t & 31;
#pragma unroll
    for (int it = 0; it < 7; ++it) {
      int tok = it * 8 + rr;
      if (tok < 49) {
        int i = (tok * 9363) >> 16, j = tok - i * 7;
        int hh = ih * 7 + i, ww = iw * 7 + j;
        float4 vv = *(const float4*)(fbuf + tok * 132 + c * 4);
        *(float4*)(ob + ((size_t)(hh * 224 + ww)) * 128 + c * 4) = vv;
      }
    }
  }
}

// ---------------------------------------------------------------------------
extern "C" void kernel_launch(void* const* d_in, const int* in_sizes, int n_in,
                              void* d_out, int out_size, void* d_ws, size_t ws_size,
                              hipStream_t stream) {
  const float* x     = (const float*)d_in[0];
  const float* ca_w1 = (const float*)d_in[3];
  const float* ca_b1 = (const float*)d_in[4];
  const float* ca_w2 = (const float*)d_in[5];
  const float* ca_b2 = (const float*)d_in[6];
  const float* sa_w  = (const float*)d_in[7];
  const float* sa_b  = (const float*)d_in[8];
  const float* w_in  = (const float*)d_in[9];
  const float* b_in  = (const float*)d_in[10];
  const float* w_out = (const float*)d_in[11];
  const float* b_out = (const float*)d_in[12];
  const float* rpe   = (const float*)d_in[13];
  float* out = (float*)d_out;

  char* ws = (char*)d_ws;
  float* pooled = (float*)(ws + 0);                       // 1024 f32
  float* sca    = (float*)(ws + 4096);                    // 1024 f32
  float* smean  = (float*)(ws + 8192);                    // 401408 f32
  float* smax   = (float*)(ws + 8192 + 1605632);          // 401408 f32
  float* ssa    = (float*)(ws + 8192 + 2 * 1605632);      // 401408 f32
  u16* wqkv_bf  = (u16*)(ws + 8192 + 3 * 1605632);                 // 49152 u16
  u16* wout_bf  = (u16*)(ws + 8192 + 3 * 1605632 + 98304);         // 16384 u16
  u16* bias_bf  = (u16*)(ws + 8192 + 3 * 1605632 + 98304 + 32768); // 16384 u16

  k0_prep<<<328, 256, 0, stream>>>(w_in, w_out, rpe, wqkv_bf, wout_bf, bias_bf, pooled);
  k1_pool<<<3136, 256, 0, stream>>>(x, pooled);
  k2_mlp <<<1, 128, 0, stream>>>(pooled, ca_w1, ca_b1, ca_w2, ca_b2, sca);
  k3_stats<<<12544, 256, 0, stream>>>(x, sca, smean, smax);
  k4_conv<<<1568, 256, 0, stream>>>(smean, smax, sa_w, sa_b, ssa);
  k5_attn<<<8192, 256, 0, stream>>>(x, sca, ssa, wqkv_bf, wout_bf, bias_bf, b_in, b_out, out);
}